// Round 3
// baseline (37.684 us; speedup 1.0000x reference)
//
#include <hip/hip_runtime.h>

// SubtitleColorConsistencyLoss — MI355X (gfx950)
// R2: single-shot tile blocks (64px x 16rows), 2048 blocks, no grid-stride.
//     Per-group span reduce (15 swizzles), per-block ~1 segment -> tiny
//     global atomic tail. launch_bounds(256,6) to push occupancy to 6/SIMD.

namespace {
constexpr int NIMG = 8;
constexpr int NCH  = 16;
constexpr int HWPX = 512 * 512;
constexpr int WIDTH = 512;
constexpr int KSEG = 65;     // labels 0..64; slot 0 doubles as background stats
constexpr int NF   = 18;     // [0]=count [1]=sqsum [2..17]=channel sums
constexpr float EPSV   = 1e-6f;
constexpr float MARGIN = 0.5f;
constexpr float LAMBDA = 0.4f;
constexpr float MINPIX = 20.0f;
}

__global__ __launch_bounds__(256, 6) void accum_kernel(
    const float* __restrict__ color,
    const int*   __restrict__ labels,
    float* __restrict__ ws)
{
    __shared__ float tab[KSEG * NF];
    const int tid = threadIdx.x;
    for (int i = tid; i < KSEG * NF; i += 256) tab[i] = 0.0f;
    __syncthreads();

    const int n = blockIdx.y;
    const float* colN = color  + (size_t)n * NCH * HWPX;
    const int*   labN = labels + (size_t)n * HWPX;

    const int grp  = tid >> 4;          // group (0..15) -> one 64-px row span
    const int l16  = tid & 15;
    const int wgrp = (tid & 63) >> 4;   // group within wave (0..3)

    const int tx = blockIdx.x & 7;      // tile col (64 px)
    const int ty = blockIdx.x >> 3;     // tile row (16 image rows)
    const int row = ty * 16 + grp;
    const int p = row * WIDTH + tx * 64 + l16 * 4;

    const int4 lab = *reinterpret_cast<const int4*>(labN + p);
    const int  lab0 = __shfl(lab.x, 0, 16);
    const bool uni_t = (lab.x == lab.y) && (lab.x == lab.z) &&
                       (lab.x == lab.w) && (lab.x == lab0);
    const unsigned long long b = __ballot((int)uni_t);
    const unsigned long long m = 0xFFFFull << (wgrp * 16);

    if ((b & m) == m) {
        // fast path: whole 64-px span has one label
        float fs[NCH];
        float sq = 0.0f;
        #pragma unroll
        for (int c = 0; c < NCH; ++c) {
            const float4 v = *reinterpret_cast<const float4*>(
                colN + (size_t)c * HWPX + p);
            fs[c] = (v.x + v.y) + (v.z + v.w);
            sq += v.x * v.x + v.y * v.y + v.z * v.z + v.w * v.w;
        }
        // reduce-scatter: lane l ends owning channel l's span total.
        #pragma unroll
        for (int c = 0; c < 8; ++c) {
            const float snd = (l16 & 8) ? fs[c] : fs[c + 8];
            const float kp  = (l16 & 8) ? fs[c + 8] : fs[c];
            fs[c] = kp + __shfl_xor(snd, 8, 16);
        }
        #pragma unroll
        for (int c = 0; c < 4; ++c) {
            const float snd = (l16 & 4) ? fs[c] : fs[c + 4];
            const float kp  = (l16 & 4) ? fs[c + 4] : fs[c];
            fs[c] = kp + __shfl_xor(snd, 4, 16);
        }
        #pragma unroll
        for (int c = 0; c < 2; ++c) {
            const float snd = (l16 & 2) ? fs[c] : fs[c + 2];
            const float kp  = (l16 & 2) ? fs[c + 2] : fs[c];
            fs[c] = kp + __shfl_xor(snd, 2, 16);
        }
        {
            const float snd = (l16 & 1) ? fs[0] : fs[1];
            const float kp  = (l16 & 1) ? fs[1] : fs[0];
            fs[0] = kp + __shfl_xor(snd, 1, 16);
        }
        sq += __shfl_xor(sq, 8, 16);
        sq += __shfl_xor(sq, 4, 16);
        sq += __shfl_xor(sq, 2, 16);
        sq += __shfl_xor(sq, 1, 16);

        float* seg = tab + lab0 * NF;
        atomicAdd(seg + 2 + l16, fs[0]);   // 16 lanes, consecutive addresses
        if (l16 == 0) {
            atomicAdd(seg + 0, 64.0f);
            atomicAdd(seg + 1, sq);
        }
    } else {
        // correctness fallback: per-pixel LDS atomics (never on this data)
        const int labv[4] = {lab.x, lab.y, lab.z, lab.w};
        for (int i = 0; i < 4; ++i) {
            float sqp = 0.0f;
            float* seg = tab + labv[i] * NF;
            for (int c = 0; c < NCH; ++c) {
                const float x = colN[(size_t)c * HWPX + p + i];
                sqp += x * x;
                atomicAdd(seg + 2 + c, x);
            }
            atomicAdd(seg + 0, 1.0f);
            atomicAdd(seg + 1, sqp);
        }
    }

    __syncthreads();
    // flush: typically only 1-2 segments nonzero per block
    float* wsN = ws + (size_t)n * KSEG * NF;
    for (int i = tid; i < KSEG * NF; i += 256) {
        const float v = tab[i];
        if (v != 0.0f) atomicAdd(wsN + i, v);
    }
}

__global__ __launch_bounds__(256) void finalize_kernel(
    const float* __restrict__ ws, float* __restrict__ out)
{
    __shared__ float mbg[NIMG][NCH];
    __shared__ float bgcnt[NIMG];
    __shared__ float r0[256], r1[256], r2[256];
    const int tid = threadIdx.x;
    if (tid < NIMG * NCH) {
        const int n = tid / NCH, c = tid % NCH;
        const float* b = ws + (size_t)n * KSEG * NF;   // slot 0 = background
        const float cnt = b[0];
        mbg[n][c] = b[2 + c] / (cnt + EPSV);
        if (c == 0) bgcnt[n] = cnt;
    }
    __syncthreads();

    float vsum = 0.0f, intraS = 0.0f, interS = 0.0f;
    for (int idx = tid; idx < NIMG * KSEG; idx += 256) {
        const int n = idx / KSEG, k = idx % KSEG;
        if (k == 0) continue;
        const float* s = ws + ((size_t)n * KSEG + k) * NF;
        const float cnt = s[0], sq = s[1];
        const float denom = cnt + EPSV;
        float d2 = 0.0f, msf = 0.0f, msm = 0.0f;
        #pragma unroll
        for (int c = 0; c < NCH; ++c) {
            const float f  = s[2 + c];
            const float mu = f / denom;
            msf += mu * f;
            msm += mu * mu;
            const float dd = mu - mbg[n][c];
            d2 += dd * dd;
        }
        const float intra = (sq - 2.0f * msf + cnt * msm) / denom;
        const float dist  = sqrtf(d2 + 1e-12f);
        const float t     = fmaxf(MARGIN - dist, 0.0f);
        const float inter = t * t;
        if ((cnt >= MINPIX) && (bgcnt[n] >= MINPIX)) {
            vsum += 1.0f; intraS += intra; interS += inter;
        }
    }
    r0[tid] = vsum; r1[tid] = intraS; r2[tid] = interS;
    __syncthreads();
    for (int sft = 128; sft; sft >>= 1) {
        if (tid < sft) {
            r0[tid] += r0[tid + sft];
            r1[tid] += r1[tid + sft];
            r2[tid] += r2[tid + sft];
        }
        __syncthreads();
    }
    if (tid == 0) {
        const float total = r0[0];
        const float safe  = fmaxf(total, 1.0f);
        out[0] = (total > 0.0f) ? (r1[0] + LAMBDA * r2[0]) / safe : 0.0f;
    }
}

extern "C" void kernel_launch(void* const* d_in, const int* in_sizes, int n_in,
                              void* d_out, int out_size, void* d_ws, size_t ws_size,
                              hipStream_t stream) {
    const float* color  = (const float*)d_in[0];
    const int*   labels = (const int*)d_in[2];
    float* ws  = (float*)d_ws;
    float* out = (float*)d_out;

    hipMemsetAsync(ws, 0, (size_t)NIMG * KSEG * NF * sizeof(float), stream);

    dim3 grid(256, NIMG);   // 2048 single-shot tile blocks (64px x 16rows)
    accum_kernel<<<grid, 256, 0, stream>>>(color, labels, ws);
    finalize_kernel<<<1, 256, 0, stream>>>(ws, out);
}